// Round 1
// baseline (651.066 us; speedup 1.0000x reference)
//
#include <hip/hip_runtime.h>

typedef unsigned short u16;
typedef __attribute__((ext_vector_type(8))) short bf16x8;
typedef __attribute__((ext_vector_type(4))) float f32x4;

__device__ __forceinline__ u16 f2bf(float f) {
  union { float f; unsigned u; } x; x.f = f;
  return (u16)((x.u + 0x7FFFu + ((x.u >> 16) & 1u)) >> 16);
}
__device__ __forceinline__ float bf2f(u16 h) {
  union { unsigned u; float f; } x; x.u = ((unsigned)h) << 16; return x.f;
}

// ---------------- prep: W fp32 -> bf16 (RNE), BN+bias folded to scale/shift ----
__global__ __launch_bounds__(256) void prep_kernel(
    const float* __restrict__ W0, const float* __restrict__ W1,
    const float* __restrict__ W2, const float* __restrict__ W3,
    const float* __restrict__ b0, const float* __restrict__ g0, const float* __restrict__ be0, const float* __restrict__ m0, const float* __restrict__ v0,
    const float* __restrict__ b1, const float* __restrict__ g1, const float* __restrict__ be1, const float* __restrict__ m1, const float* __restrict__ v1,
    const float* __restrict__ b2, const float* __restrict__ g2, const float* __restrict__ be2, const float* __restrict__ m2, const float* __restrict__ v2,
    const float* __restrict__ b3, const float* __restrict__ g3, const float* __restrict__ be3, const float* __restrict__ m3, const float* __restrict__ v3,
    u16* __restrict__ Wb, float* __restrict__ sc, float* __restrict__ sh)
{
  int i = blockIdx.x * 256 + threadIdx.x;
  if (i < 499712) {
    float w;
    if (i < 327680)      w = W0[i];
    else if (i < 458752) w = W1[i - 327680];
    else if (i < 491520) w = W2[i - 458752];
    else                 w = W3[i - 491520];
    Wb[i] = f2bf(w);
  }
  if (i < 960) {
    const float *B, *G, *BE, *M, *V; int c;
    if (i < 512)      { c = i;       B = b0; G = g0; BE = be0; M = m0; V = v0; }
    else if (i < 768) { c = i - 512; B = b1; G = g1; BE = be1; M = m1; V = v1; }
    else if (i < 896) { c = i - 768; B = b2; G = g2; BE = be2; M = m2; V = v2; }
    else              { c = i - 896; B = b3; G = g3; BE = be3; M = m3; V = v3; }
    float inv = G[c] / sqrtf(V[c] + 1e-5f);
    sc[i] = inv;
    sh[i] = (B[c] - M[c]) * inv + BE[c];
  }
}

// ---------------- fused 4-layer GEMM helpers ----------------
// A (weights) row-major [Cout][Cin] bf16 in global (L2-resident).
// B (activations) in LDS as [n][k] bf16, row stride rowB bytes, XOR-swizzled:
//   byte ^= ((n & 7) << 4).
// MFMA 16x16x32 bf16: A lane: row=l&15, k=8*(l>>4)+j. B lane: col=l&15, same k.
// C/D: col=l&15, row=(l>>4)*4+reg.
template<int MT, int NT, int CIN>
__device__ __forceinline__ void gemm_lds(const u16* __restrict__ Wl,
                                         const u16* __restrict__ src, int rowB,
                                         int mrow0, int ntb, int lane,
                                         f32x4 (&acc)[MT][NT])
{
  const int r16 = lane & 15, g = lane >> 4;
  #pragma unroll 2
  for (int ks = 0; ks < CIN / 32; ++ks) {
    const int k0 = ks * 32 + g * 8;
    bf16x8 a[MT], bb[NT];
    #pragma unroll
    for (int mi = 0; mi < MT; ++mi)
      a[mi] = *reinterpret_cast<const bf16x8*>(Wl + (mrow0 + mi * 16 + r16) * CIN + k0);
    #pragma unroll
    for (int nt = 0; nt < NT; ++nt) {
      const int n = (ntb + nt) * 16 + r16;
      const unsigned byte = ((unsigned)(n * rowB + k0 * 2)) ^ ((unsigned)((n & 7) << 4));
      bb[nt] = *reinterpret_cast<const bf16x8*>(reinterpret_cast<const char*>(src) + byte);
    }
    #pragma unroll
    for (int mi = 0; mi < MT; ++mi)
      #pragma unroll
      for (int nt = 0; nt < NT; ++nt)
        acc[mi][nt] = __builtin_amdgcn_mfma_f32_16x16x32_bf16(a[mi], bb[nt], acc[mi][nt], 0, 0, 0);
  }
}

// scale/shift/ReLU epilogue -> bf16 activation tile in LDS ([n][c], swizzled)
template<int MT, int NT>
__device__ __forceinline__ void store_act_lds(f32x4 (&acc)[MT][NT],
                                              const float* __restrict__ sc,
                                              const float* __restrict__ sh,
                                              int mrow0, int ntb, int lane,
                                              u16* __restrict__ dst, int rowB)
{
  const int r16 = lane & 15, g = lane >> 4;
  #pragma unroll
  for (int mi = 0; mi < MT; ++mi) {
    const int c0 = mrow0 + mi * 16 + g * 4;
    const f32x4 s4 = *reinterpret_cast<const f32x4*>(sc + c0);
    const f32x4 h4 = *reinterpret_cast<const f32x4*>(sh + c0);
    #pragma unroll
    for (int nt = 0; nt < NT; ++nt) {
      const int n = (ntb + nt) * 16 + r16;
      float r0 = fmaxf(acc[mi][nt][0] * s4[0] + h4[0], 0.f);
      float r1 = fmaxf(acc[mi][nt][1] * s4[1] + h4[1], 0.f);
      float r2 = fmaxf(acc[mi][nt][2] * s4[2] + h4[2], 0.f);
      float r3 = fmaxf(acc[mi][nt][3] * s4[3] + h4[3], 0.f);
      uint2 pk;
      pk.x = (unsigned)f2bf(r0) | ((unsigned)f2bf(r1) << 16);
      pk.y = (unsigned)f2bf(r2) | ((unsigned)f2bf(r3) << 16);
      const unsigned byte = ((unsigned)(n * rowB + c0 * 2)) ^ ((unsigned)((n & 7) << 4));
      *reinterpret_cast<uint2*>(reinterpret_cast<char*>(dst) + byte) = pk;
    }
  }
}

// ---------------- fused 4-layer kernel ----------------
// Block: 512 threads (8 waves), one (batch b, 64-pixel j-tile).
// LDS: Xs [64][640] bf16 (81920 B) | Y0s [64][512] (65536 B); Y1s/Y2s overlay Xs.
__global__ __launch_bounds__(512) void fused4_kernel(
    const float* __restrict__ gp, const u16* __restrict__ Wb,
    const float* __restrict__ sc, const float* __restrict__ sh,
    u16* __restrict__ x3)
{
  __shared__ u16 smem[73728];
  u16* Xs  = smem;           // row stride 1280 B
  u16* Y0s = smem + 40960;   // row stride 1024 B
  u16* Y1s = smem;           // row stride  512 B
  u16* Y2s = smem + 16384;   // row stride  256 B

  const int tid  = threadIdx.x;
  const int lane = tid & 63;
  const int w    = tid >> 6;
  const int r16  = lane & 15, g = lane >> 4;

  const int b  = blockIdx.x >> 9;
  const int jt = blockIdx.x & 511;
  const int j0 = jt << 6;

  // ---- stage X tile: [64 px][640 ch] fp32 -> bf16, swizzled
  {
    const float* xb = gp + (size_t)b * (640 * 32768) + j0;
    const int n  = tid & 63;
    const int kb = (tid >> 6) * 8;                 // wave-uniform
    const unsigned swz = (unsigned)((n & 7) << 4);
    #pragma unroll 2
    for (int it = 0; it < 10; ++it) {
      const int k0 = it * 64 + kb;
      float v[8];
      #pragma unroll
      for (int kk = 0; kk < 8; ++kk)
        v[kk] = xb[(size_t)(k0 + kk) * 32768 + n];
      bf16x8 pk;
      #pragma unroll
      for (int kk = 0; kk < 8; ++kk)
        pk[kk] = (short)f2bf(v[kk]);
      const unsigned byte = ((unsigned)(n * 1280 + k0 * 2)) ^ swz;
      *reinterpret_cast<bf16x8*>(reinterpret_cast<char*>(Xs) + byte) = pk;
    }
  }
  __syncthreads();

  // ---- phase 0: 640 -> 512 (wave w owns rows w*64 .. w*64+63)
  {
    f32x4 acc0[4][4] = {};
    gemm_lds<4, 4, 640>(Wb, Xs, 1280, w * 64, 0, lane, acc0);
    store_act_lds<4, 4>(acc0, sc, sh, w * 64, 0, lane, Y0s, 1024);
  }
  __syncthreads();

  // ---- phase 1: 512 -> 256 (wave w owns rows w*32 .. w*32+31)
  {
    f32x4 acc1[2][4] = {};
    gemm_lds<2, 4, 512>(Wb + 327680, Y0s, 1024, w * 32, 0, lane, acc1);
    store_act_lds<2, 4>(acc1, sc + 512, sh + 512, w * 32, 0, lane, Y1s, 512);
  }
  __syncthreads();

  // ---- phase 2: 256 -> 128 (wave w owns rows w*16 .. w*16+15)
  {
    f32x4 acc2[1][4] = {};
    gemm_lds<1, 4, 256>(Wb + 458752, Y1s, 512, w * 16, 0, lane, acc2);
    store_act_lds<1, 4>(acc2, sc + 768, sh + 768, w * 16, 0, lane, Y2s, 256);
  }
  __syncthreads();

  // ---- phase 3: 128 -> 64 (wave w: m-tile w&3, n-tiles 2*(w>>2)+{0,1})
  {
    f32x4 acc3[1][2] = {};
    const int ntb = (w >> 2) * 2;
    gemm_lds<1, 2, 128>(Wb + 491520, Y2s, 256, (w & 3) * 16, ntb, lane, acc3);

    const int c0 = (w & 3) * 16 + g * 4;
    const f32x4 s4 = *reinterpret_cast<const f32x4*>(sc + 896 + c0);
    const f32x4 h4 = *reinterpret_cast<const f32x4*>(sh + 896 + c0);
    u16* x3b = x3 + ((size_t)b << 21) + j0;        // b*64*32768
    #pragma unroll
    for (int nt = 0; nt < 2; ++nt) {
      const int n = (ntb + nt) * 16 + r16;
      #pragma unroll
      for (int r = 0; r < 4; ++r) {
        float vv = fmaxf(acc3[0][nt][r] * s4[r] + h4[r], 0.f);
        x3b[(size_t)(c0 + r) * 32768 + n] = f2bf(vv);
      }
    }
  }
}

// ---------------- softmax over K + weighted sum with xyz ----------------
__global__ __launch_bounds__(256) void softmax_ws_kernel(
    const u16* __restrict__ x3, const float* __restrict__ xyz,
    float* __restrict__ out)
{
  const int tid = blockIdx.x * 256 + threadIdx.x;   // 0 .. 524287
  const int b = tid >> 16;
  const int rem = tid & 65535;
  const int d = rem >> 10;
  const int s = rem & 1023;

  const u16* xp = x3 + ((size_t)(b * 64 + d) << 15) + s;
  float p[32];
  float mx = -1e30f;
  #pragma unroll
  for (int k = 0; k < 32; ++k) { p[k] = bf2f(xp[(size_t)k << 10]); mx = fmaxf(mx, p[k]); }
  float sum = 0.f;
  #pragma unroll
  for (int k = 0; k < 32; ++k) { p[k] = __expf(p[k] - mx); sum += p[k]; }
  const float inv = 1.0f / sum;

  const float* zp = xyz + (size_t)b * (3 * 32768) + s;
  #pragma unroll
  for (int c = 0; c < 3; ++c) {
    float a = 0.f;
    #pragma unroll
    for (int k = 0; k < 32; ++k) a += p[k] * zp[c * 32768 + (k << 10)];
    out[((size_t)((b * 3 + c) * 64 + d) << 10) + s] = a * inv;
  }
}

// ---------------- launcher ----------------
extern "C" void kernel_launch(void* const* d_in, const int* in_sizes, int n_in,
                              void* d_out, int out_size, void* d_ws, size_t ws_size,
                              hipStream_t stream) {
  const float* xyz = (const float*)d_in[0];
  const float* gp  = (const float*)d_in[1];
  const float* W0 = (const float*)d_in[2];
  const float* W1 = (const float*)d_in[8];
  const float* W2 = (const float*)d_in[14];
  const float* W3 = (const float*)d_in[20];

  char* ws = (char*)d_ws;
  u16*   Wb = (u16*)ws;                       // 499712 bf16 -> 999424 B
  float* sc = (float*)(ws + 999424);          // 960 f32
  float* sh = (float*)(ws + 1003264);         // 960 f32
  u16*   x3 = (u16*)(ws + 1007104);           // 8*64*32768 bf16 = 33.5 MB

  prep_kernel<<<1953, 256, 0, stream>>>(
      W0, W1, W2, W3,
      (const float*)d_in[3],  (const float*)d_in[4],  (const float*)d_in[5],  (const float*)d_in[6],  (const float*)d_in[7],
      (const float*)d_in[9],  (const float*)d_in[10], (const float*)d_in[11], (const float*)d_in[12], (const float*)d_in[13],
      (const float*)d_in[15], (const float*)d_in[16], (const float*)d_in[17], (const float*)d_in[18], (const float*)d_in[19],
      (const float*)d_in[21], (const float*)d_in[22], (const float*)d_in[23], (const float*)d_in[24], (const float*)d_in[25],
      Wb, sc, sh);

  fused4_kernel<<<4096, 512, 0, stream>>>(gp, Wb, sc, sh, x3);

  softmax_ws_kernel<<<2048, 256, 0, stream>>>(x3, xyz, (float*)d_out);
}

// Round 2
// 572.777 us; speedup vs baseline: 1.1367x; 1.1367x over previous
//
#include <hip/hip_runtime.h>

typedef unsigned short u16;
typedef __attribute__((ext_vector_type(8))) short bf16x8;
typedef __attribute__((ext_vector_type(4))) float f32x4;

__device__ __forceinline__ u16 f2bf(float f) {
  union { float f; unsigned u; } x; x.f = f;
  return (u16)((x.u + 0x7FFFu + ((x.u >> 16) & 1u)) >> 16);
}
__device__ __forceinline__ float bf2f(u16 h) {
  union { unsigned u; float f; } x; x.u = ((unsigned)h) << 16; return x.f;
}

// ---------------- prep: W fp32 -> bf16 (RNE), BN+bias folded to scale/shift ----
__global__ __launch_bounds__(256) void prep_kernel(
    const float* __restrict__ W0, const float* __restrict__ W1,
    const float* __restrict__ W2, const float* __restrict__ W3,
    const float* __restrict__ b0, const float* __restrict__ g0, const float* __restrict__ be0, const float* __restrict__ m0, const float* __restrict__ v0,
    const float* __restrict__ b1, const float* __restrict__ g1, const float* __restrict__ be1, const float* __restrict__ m1, const float* __restrict__ v1,
    const float* __restrict__ b2, const float* __restrict__ g2, const float* __restrict__ be2, const float* __restrict__ m2, const float* __restrict__ v2,
    const float* __restrict__ b3, const float* __restrict__ g3, const float* __restrict__ be3, const float* __restrict__ m3, const float* __restrict__ v3,
    u16* __restrict__ Wb, float* __restrict__ sc, float* __restrict__ sh)
{
  int i = blockIdx.x * 256 + threadIdx.x;
  if (i < 499712) {
    float w;
    if (i < 327680)      w = W0[i];
    else if (i < 458752) w = W1[i - 327680];
    else if (i < 491520) w = W2[i - 458752];
    else                 w = W3[i - 491520];
    Wb[i] = f2bf(w);
  }
  if (i < 960) {
    const float *B, *G, *BE, *M, *V; int c;
    if (i < 512)      { c = i;       B = b0; G = g0; BE = be0; M = m0; V = v0; }
    else if (i < 768) { c = i - 512; B = b1; G = g1; BE = be1; M = m1; V = v1; }
    else if (i < 896) { c = i - 768; B = b2; G = g2; BE = be2; M = m2; V = v2; }
    else              { c = i - 896; B = b3; G = g3; BE = be3; M = m3; V = v3; }
    float inv = G[c] / sqrtf(V[c] + 1e-5f);
    sc[i] = inv;
    sh[i] = (B[c] - M[c]) * inv + BE[c];
  }
}

// ---------------- shared GEMM helpers (16x16x32 bf16) ----------------
// B (activations) in LDS as [px][ch] bf16, row stride rowB bytes, swizzle byte ^= ((px&7)<<4).
// A lane: row=l&15, k=8*(l>>4)+j.  B lane: col(px)=l&15, same k.  C/D: col=l&15, row=(l>>4)*4+reg.
template<int MT, int NT, int CIN>
__device__ __forceinline__ void gemm_lds(const u16* __restrict__ Wl,
                                         const u16* __restrict__ src, int rowB,
                                         int mrow0, int ntb, int lane,
                                         f32x4 (&acc)[MT][NT])
{
  const int r16 = lane & 15, g = lane >> 4;
  #pragma unroll 2
  for (int ks = 0; ks < CIN / 32; ++ks) {
    const int k0 = ks * 32 + g * 8;
    bf16x8 a[MT], bb[NT];
    #pragma unroll
    for (int mi = 0; mi < MT; ++mi)
      a[mi] = *reinterpret_cast<const bf16x8*>(Wl + (mrow0 + mi * 16 + r16) * CIN + k0);
    #pragma unroll
    for (int nt = 0; nt < NT; ++nt) {
      const int n = (ntb + nt) * 16 + r16;
      const unsigned byte = ((unsigned)(n * rowB + k0 * 2)) ^ ((unsigned)((n & 7) << 4));
      bb[nt] = *reinterpret_cast<const bf16x8*>(reinterpret_cast<const char*>(src) + byte);
    }
    #pragma unroll
    for (int mi = 0; mi < MT; ++mi)
      #pragma unroll
      for (int nt = 0; nt < NT; ++nt)
        acc[mi][nt] = __builtin_amdgcn_mfma_f32_16x16x32_bf16(a[mi], bb[nt], acc[mi][nt], 0, 0, 0);
  }
}

template<int MT, int NT>
__device__ __forceinline__ void store_act_lds(f32x4 (&acc)[MT][NT],
                                              const float* __restrict__ sc,
                                              const float* __restrict__ sh,
                                              int mrow0, int ntb, int lane,
                                              u16* __restrict__ dst, int rowB)
{
  const int r16 = lane & 15, g = lane >> 4;
  #pragma unroll
  for (int mi = 0; mi < MT; ++mi) {
    const int c0 = mrow0 + mi * 16 + g * 4;
    const f32x4 s4 = *reinterpret_cast<const f32x4*>(sc + c0);
    const f32x4 h4 = *reinterpret_cast<const f32x4*>(sh + c0);
    #pragma unroll
    for (int nt = 0; nt < NT; ++nt) {
      const int n = (ntb + nt) * 16 + r16;
      float r0 = fmaxf(acc[mi][nt][0] * s4[0] + h4[0], 0.f);
      float r1 = fmaxf(acc[mi][nt][1] * s4[1] + h4[1], 0.f);
      float r2 = fmaxf(acc[mi][nt][2] * s4[2] + h4[2], 0.f);
      float r3 = fmaxf(acc[mi][nt][3] * s4[3] + h4[3], 0.f);
      uint2 pk;
      pk.x = (unsigned)f2bf(r0) | ((unsigned)f2bf(r1) << 16);
      pk.y = (unsigned)f2bf(r2) | ((unsigned)f2bf(r3) << 16);
      const unsigned byte = ((unsigned)(n * rowB + c0 * 2)) ^ ((unsigned)((n & 7) << 4));
      *reinterpret_cast<uint2*>(reinterpret_cast<char*>(dst) + byte) = pk;
    }
  }
}

// ---------------- fused 4-layer kernel ----------------
// 512 threads (8 waves), one (batch b, 64-pixel tile). LDS = 80 KB exactly -> 2 blocks/CU.
//   Xs  [64px][128ch] stride 256B  (16 KB)  -- X k-chunk buffer; later reused as Y2
//   Y0s [64px][512ch] stride 1024B (64 KB)  -- layer0 out; later reused as Y1 (stride 512B)
// Phase0 = 5 chunks of 128 input channels, accumulated in regs; next chunk's global
// loads are issued BEFORE current chunk's MFMA (T14 async-stage split).
__global__ __launch_bounds__(512, 4) void fused4_kernel(
    const float* __restrict__ gp, const u16* __restrict__ Wb,
    const float* __restrict__ sc, const float* __restrict__ sh,
    u16* __restrict__ x3)
{
  __shared__ u16 smem[40960];   // 81920 B
  u16* Xs  = smem;              // [64][128] stride 256B (swz); also Y2
  u16* Y0s = smem + 8192;       // [64][512] stride 1024B (swz); also Y1 (stride 512B)

  const int tid  = threadIdx.x;
  const int lane = tid & 63;
  const int w    = tid >> 6;
  const int r16  = lane & 15, g = lane >> 4;

  const int b  = blockIdx.x >> 9;
  const int jt = blockIdx.x & 511;
  const int j0 = jt << 6;

  // staging task: 2 pixels (pxq*2, pxq*2+1) x 8 channels (cho*8..+7) per chunk
  const int pxq = tid & 31;
  const int cho = tid >> 5;     // 0..15
  const float* gsrc = gp + (size_t)b * (640u * 32768u)
                         + (size_t)(cho * 8) * 32768u + (unsigned)(j0 + pxq * 2);

  float2 v[8];
  const int px0 = pxq * 2, px1 = px0 + 1;
  const unsigned wb0 = ((unsigned)(px0 * 256 + cho * 16)) ^ ((unsigned)((px0 & 7) << 4));
  const unsigned wb1 = ((unsigned)(px1 * 256 + cho * 16)) ^ ((unsigned)((px1 & 7) << 4));

#define LOADC(c) { const float* s_ = gsrc + (size_t)(c) * (128u * 32768u); \
    _Pragma("unroll") for (int kk = 0; kk < 8; ++kk) \
      v[kk] = *reinterpret_cast<const float2*>(s_ + (size_t)kk * 32768u); }
#define WRITEC() { bf16x8 pa, pb; \
    _Pragma("unroll") for (int kk = 0; kk < 8; ++kk) { pa[kk] = (short)f2bf(v[kk].x); pb[kk] = (short)f2bf(v[kk].y); } \
    *reinterpret_cast<bf16x8*>(reinterpret_cast<char*>(Xs) + wb0) = pa; \
    *reinterpret_cast<bf16x8*>(reinterpret_cast<char*>(Xs) + wb1) = pb; }

  // ---- phase 0: 640 -> 512, five 128-ch chunks, reg accumulation
  f32x4 acc0[4][4] = {};
  LOADC(0); WRITEC();
  __syncthreads();
  #pragma unroll 1
  for (int c = 0; c < 5; ++c) {
    if (c < 4) LOADC(c + 1);                    // issue next chunk's loads early
    // MFMA over chunk c (4 k-steps)
    #pragma unroll 2
    for (int ks = 0; ks < 4; ++ks) {
      const int k0 = ks * 32 + g * 8;           // within chunk
      bf16x8 a[4], bb[4];
      #pragma unroll
      for (int mi = 0; mi < 4; ++mi)
        a[mi] = *reinterpret_cast<const bf16x8*>(Wb + (w * 64 + mi * 16 + r16) * 640 + c * 128 + k0);
      #pragma unroll
      for (int nt = 0; nt < 4; ++nt) {
        const int n = nt * 16 + r16;
        const unsigned byte = ((unsigned)(n * 256 + k0 * 2)) ^ ((unsigned)((n & 7) << 4));
        bb[nt] = *reinterpret_cast<const bf16x8*>(reinterpret_cast<const char*>(Xs) + byte);
      }
      #pragma unroll
      for (int mi = 0; mi < 4; ++mi)
        #pragma unroll
        for (int nt = 0; nt < 4; ++nt)
          acc0[mi][nt] = __builtin_amdgcn_mfma_f32_16x16x32_bf16(a[mi], bb[nt], acc0[mi][nt], 0, 0, 0);
    }
    if (c < 4) {
      __syncthreads();                          // all waves done reading chunk c
      WRITEC();                                 // overwrite Xs with chunk c+1
      __syncthreads();                          // chunk c+1 visible
    }
  }
  // Y0 store (does not touch Xs; no barrier needed before)
  store_act_lds<4, 4>(acc0, sc, sh, w * 64, 0, lane, Y0s, 1024);
  __syncthreads();

  // ---- phase 1: 512 -> 256
  {
    f32x4 acc1[2][4] = {};
    gemm_lds<2, 4, 512>(Wb + 327680, Y0s, 1024, w * 32, 0, lane, acc1);
    __syncthreads();                            // all waves done reading Y0
    store_act_lds<2, 4>(acc1, sc + 512, sh + 512, w * 32, 0, lane, Y0s, 512);  // Y1 overlays Y0
    __syncthreads();
  }

  // ---- phase 2: 256 -> 128
  {
    f32x4 acc2[1][4] = {};
    gemm_lds<1, 4, 256>(Wb + 458752, Y0s, 512, w * 16, 0, lane, acc2);
    // Y2 -> Xs region (not read since phase 0; disjoint from Y1 reads)
    store_act_lds<1, 4>(acc2, sc + 768, sh + 768, w * 16, 0, lane, Xs, 256);
    __syncthreads();
  }

  // ---- phase 3: 128 -> 64 (wave w: m-tile w&3, n-tiles 2*(w>>2)+{0,1})
  {
    f32x4 acc3[1][2] = {};
    const int ntb = (w >> 2) * 2;
    gemm_lds<1, 2, 128>(Wb + 491520, Xs, 256, (w & 3) * 16, ntb, lane, acc3);

    const int c0 = (w & 3) * 16 + g * 4;
    const f32x4 s4 = *reinterpret_cast<const f32x4*>(sc + 896 + c0);
    const f32x4 h4 = *reinterpret_cast<const f32x4*>(sh + 896 + c0);
    u16* x3b = x3 + ((size_t)b << 21) + j0;     // b*64*32768
    #pragma unroll
    for (int nt = 0; nt < 2; ++nt) {
      const int n = (ntb + nt) * 16 + r16;
      #pragma unroll
      for (int r = 0; r < 4; ++r) {
        float vv = fmaxf(acc3[0][nt][r] * s4[r] + h4[r], 0.f);
        x3b[(size_t)(c0 + r) * 32768 + n] = f2bf(vv);
      }
    }
  }
#undef LOADC
#undef WRITEC
}

// ---------------- softmax over K + weighted sum with xyz ----------------
__global__ __launch_bounds__(256) void softmax_ws_kernel(
    const u16* __restrict__ x3, const float* __restrict__ xyz,
    float* __restrict__ out)
{
  const int tid = blockIdx.x * 256 + threadIdx.x;   // 0 .. 524287
  const int b = tid >> 16;
  const int rem = tid & 65535;
  const int d = rem >> 10;
  const int s = rem & 1023;

  const u16* xp = x3 + ((size_t)(b * 64 + d) << 15) + s;
  float p[32];
  float mx = -1e30f;
  #pragma unroll
  for (int k = 0; k < 32; ++k) { p[k] = bf2f(xp[(size_t)k << 10]); mx = fmaxf(mx, p[k]); }
  float sum = 0.f;
  #pragma unroll
  for (int k = 0; k < 32; ++k) { p[k] = __expf(p[k] - mx); sum += p[k]; }
  const float inv = 1.0f / sum;

  const float* zp = xyz + (size_t)b * (3 * 32768) + s;
  #pragma unroll
  for (int c = 0; c < 3; ++c) {
    float a = 0.f;
    #pragma unroll
    for (int k = 0; k < 32; ++k) a += p[k] * zp[c * 32768 + (k << 10)];
    out[((size_t)((b * 3 + c) * 64 + d) << 10) + s] = a * inv;
  }
}

// ---------------- launcher ----------------
extern "C" void kernel_launch(void* const* d_in, const int* in_sizes, int n_in,
                              void* d_out, int out_size, void* d_ws, size_t ws_size,
                              hipStream_t stream) {
  const float* xyz = (const float*)d_in[0];
  const float* gp  = (const float*)d_in[1];
  const float* W0 = (const float*)d_in[2];
  const float* W1 = (const float*)d_in[8];
  const float* W2 = (const float*)d_in[14];
  const float* W3 = (const float*)d_in[20];

  char* ws = (char*)d_ws;
  u16*   Wb = (u16*)ws;                       // 499712 bf16 -> 999424 B
  float* sc = (float*)(ws + 999424);          // 960 f32
  float* sh = (float*)(ws + 1003264);         // 960 f32
  u16*   x3 = (u16*)(ws + 1007104);           // 8*64*32768 bf16 = 33.5 MB

  prep_kernel<<<1953, 256, 0, stream>>>(
      W0, W1, W2, W3,
      (const float*)d_in[3],  (const float*)d_in[4],  (const float*)d_in[5],  (const float*)d_in[6],  (const float*)d_in[7],
      (const float*)d_in[9],  (const float*)d_in[10], (const float*)d_in[11], (const float*)d_in[12], (const float*)d_in[13],
      (const float*)d_in[15], (const float*)d_in[16], (const float*)d_in[17], (const float*)d_in[18], (const float*)d_in[19],
      (const float*)d_in[21], (const float*)d_in[22], (const float*)d_in[23], (const float*)d_in[24], (const float*)d_in[25],
      Wb, sc, sh);

  fused4_kernel<<<4096, 512, 0, stream>>>(gp, Wb, sc, sh, x3);

  softmax_ws_kernel<<<2048, 256, 0, stream>>>(x3, xyz, (float*)d_out);
}